// Round 1
// baseline (888.892 us; speedup 1.0000x reference)
//
#include <hip/hip_runtime.h>

#define N_NODES 100000
#define N_EDGES 640000
#define HIDDEN  128
#define N_USERS 1000
#define CAP     64   // max in-degree bucket capacity (Poisson(6.4): P(>40) ~ 1e-14)

using u16 = unsigned short;
using u32 = unsigned int;

using short8  = __attribute__((ext_vector_type(8))) short;  // 8 bf16 (4 VGPR) MFMA frag
using floatx4 = __attribute__((ext_vector_type(4))) float;  // 4 f32 acc frag

__device__ __forceinline__ u16 f2bf(float f) {
  u32 u = __float_as_uint(f);
  u32 r = u + 0x7FFFu + ((u >> 16) & 1u);   // RNE
  return (u16)(r >> 16);
}
__device__ __forceinline__ float bflo2f(u32 v) { return __uint_as_float(v << 16); }

// ---------------- conversion kernels ----------------
__global__ void conv_bf16x4(const float* __restrict__ in, u16* __restrict__ out, int n4) {
  int i = blockIdx.x * 256 + threadIdx.x;
  if (i >= n4) return;
  float4 v = ((const float4*)in)[i];
  u32 lo = (u32)f2bf(v.x) | ((u32)f2bf(v.y) << 16);
  u32 hi = (u32)f2bf(v.z) | ((u32)f2bf(v.w) << 16);
  ((uint2*)out)[i] = make_uint2(lo, hi);
}

// W [128][N] f32 row-major -> BT [Npad][128] bf16 (transposed, zero-padded rows)
__global__ void conv_wT(const float* __restrict__ W, u16* __restrict__ BT, int N, int total) {
  int idx = blockIdx.x * 256 + threadIdx.x;
  if (idx >= total) return;
  int n = idx >> 7, k = idx & 127;
  float v = (n < N) ? W[(size_t)k * N + n] : 0.f;
  BT[idx] = f2bf(v);
}

// ---------------- graph prep ----------------
__global__ void deg_kernel(const int* __restrict__ col, const float* __restrict__ w,
                           float* __restrict__ deg, int E) {
  int i = blockIdx.x * 256 + threadIdx.x;
  if (i < E) atomicAdd(&deg[col[i]], w[i]);
}

__global__ void dis_kernel(const float* __restrict__ deg, float* __restrict__ dis, int M) {
  int i = blockIdx.x * 256 + threadIdx.x;
  if (i < M) {
    float d = deg[i];
    dis[i] = d > 0.f ? rsqrtf(d) : 0.f;
  }
}

__global__ void bucket_kernel(const int* __restrict__ row, const int* __restrict__ col,
                              const float* __restrict__ w, const float* __restrict__ dis,
                              int* __restrict__ counts, int* __restrict__ srcs,
                              float* __restrict__ norms, int E) {
  int i = blockIdx.x * 256 + threadIdx.x;
  if (i >= E) return;
  int r = row[i], c = col[i];
  int pos = atomicAdd(&counts[c], 1);
  if (pos < CAP) {
    size_t slot = ((size_t)c << 6) + (size_t)pos;
    srcs[slot] = r;
    norms[slot] = dis[r] * w[i] * dis[c];
  }
}

// ---------------- aggregation: out[n] = bf16( b + sum_e norm*h[src] ) ----------------
// one wave per node; lane handles 2 hidden dims (ushort2 = 1 u32)
__global__ __launch_bounds__(256)
void agg_kernel(const u16* __restrict__ hb, const int* __restrict__ counts,
                const int* __restrict__ srcs, const float* __restrict__ norms,
                const float* __restrict__ bias, u16* __restrict__ out, int M) {
  int wid  = threadIdx.x >> 6;
  int lane = threadIdx.x & 63;
  int n = blockIdx.x * 4 + wid;
  if (n >= M) return;
  int cnt = counts[n];
  cnt = cnt < CAP ? cnt : CAP;
  const int*   sp = srcs  + ((size_t)n << 6);
  const float* wp = norms + ((size_t)n << 6);
  float ax = 0.f, ay = 0.f;
  for (int e = 0; e < cnt; ++e) {
    int s   = sp[e];
    float w = wp[e];
    u32 hv = ((const u32*)hb)[((size_t)s << 6) + lane];
    ax += w * bflo2f(hv & 0xFFFFu);
    ay += w * __uint_as_float(hv & 0xFFFF0000u);
  }
  float2 b = ((const float2*)bias)[lane];
  u32 lo = (u32)f2bf(ax + b.x);
  u32 hi = (u32)f2bf(ay + b.y);
  ((u32*)out)[((size_t)n << 6) + lane] = lo | (hi << 16);
}

// ---------------- MFMA GEMM: C[M x N] = A[M x 128] @ B[128 x N] ----------------
// A row-major bf16; B pre-transposed: BT[Npad][128] bf16.
// block: 256 thr = 4 waves (2x2), block tile 128x128, wave tile 64x64 (4x4 of 16x16x32).
// LDS: As/Bs 128x128 bf16 each, XOR-swizzled 16B chunks (no padding) = 64 KB total.
template<bool F32OUT>
__global__ __launch_bounds__(256, 2)
void gemm_mfma(const u16* __restrict__ A, const u16* __restrict__ BT,
               float* __restrict__ outf, u16* __restrict__ outb,
               const float* __restrict__ bias,
               int M, int Nstore, int ldout) {
  __shared__ u16 As[128 * 128];
  __shared__ u16 Bs[128 * 128];
  const int m0 = blockIdx.x * 128;
  const int n0 = blockIdx.y * 128;
  const int tid = threadIdx.x;

  // cooperative staging: 2048 chunks of 16B; chunk c of row r goes to column-chunk c^(r&15)
  for (int i = 0; i < 8; ++i) {
    int chunk = tid + i * 256;
    int row = chunk >> 4;
    int c   = chunk & 15;
    int sw  = ((c ^ (row & 15)) << 3);
    uint4 av = {0u, 0u, 0u, 0u};
    int gr = m0 + row;
    if (gr < M) av = *(const uint4*)(A + ((size_t)gr << 7) + (c << 3));
    *(uint4*)(&As[(row << 7) + sw]) = av;
    uint4 bv = *(const uint4*)(BT + ((size_t)(n0 + row) << 7) + (c << 3));
    *(uint4*)(&Bs[(row << 7) + sw]) = bv;
  }
  __syncthreads();

  const int wid  = tid >> 6, lane = tid & 63;
  const int wr = (wid >> 1) << 6;       // wave row origin within block tile
  const int wc = (wid & 1) << 6;        // wave col origin
  const int lm = lane & 15, quad = lane >> 4;

  floatx4 acc[4][4] = {};
  for (int ks = 0; ks < 4; ++ks) {
    int cks = ks * 4 + quad;            // 16B-chunk index along K for this lane
    int sw  = ((cks ^ lm) << 3);
    short8 a[4], b[4];
    for (int i = 0; i < 4; ++i)
      a[i] = *(const short8*)(&As[((wr + i * 16 + lm) << 7) + sw]);
    for (int j = 0; j < 4; ++j)
      b[j] = *(const short8*)(&Bs[((wc + j * 16 + lm) << 7) + sw]);
    for (int i = 0; i < 4; ++i)
      for (int j = 0; j < 4; ++j)
        acc[i][j] = __builtin_amdgcn_mfma_f32_16x16x32_bf16(a[i], b[j], acc[i][j], 0, 0, 0);
  }

  // epilogue: D[row = quad*4 + r][col = lm] per 16x16 tile (m89-verified layout)
  for (int i = 0; i < 4; ++i) {
    int rb = m0 + wr + i * 16 + quad * 4;
    for (int j = 0; j < 4; ++j) {
      int col = n0 + wc + j * 16 + lm;
      if (col < Nstore) {
        float bv = F32OUT ? bias[col] : 0.f;
        for (int r = 0; r < 4; ++r) {
          int row = rb + r;
          if (row < M) {
            float v = acc[i][j][r];
            if (F32OUT) outf[(size_t)row * ldout + col] = v + bv;
            else        outb[((size_t)row << 7) + col]  = f2bf(v);
          }
        }
      }
    }
  }
}

// ---------------- launch ----------------
extern "C" void kernel_launch(void* const* d_in, const int* in_sizes, int n_in,
                              void* d_out, int out_size, void* d_ws, size_t ws_size,
                              hipStream_t stream) {
  const int*   eidx = (const int*)d_in[0];
  const int*   erow = eidx;
  const int*   ecol = eidx + N_EDGES;
  const float* ew   = (const float*)d_in[1];
  const float* emb  = (const float*)d_in[2];
  const float* W1   = (const float*)d_in[3];
  const float* b1   = (const float*)d_in[4];
  const float* W2   = (const float*)d_in[5];
  const float* b2   = (const float*)d_in[6];
  const float* Wp   = (const float*)d_in[7];
  const float* bp   = (const float*)d_in[8];
  float* out = (float*)d_out;

  const int M = N_NODES, E = N_EDGES;

  // workspace carve (all 128B-aligned sections)
  char* p = (char*)d_ws;
  float* deg    = (float*)p;  p += 400128;           // 100000 f32
  int*   counts = (int*)p;    p += 400128;           // 100000 i32 (adjacent to deg for one memset)
  float* dis    = (float*)p;  p += 400128;
  int*   srcs   = (int*)p;    p += (size_t)M * CAP * 4;   // 25.6 MB
  float* norms  = (float*)p;  p += (size_t)M * CAP * 4;   // 25.6 MB
  u16*   embb   = (u16*)p;    p += (size_t)M * 128 * 2;   // 25.6 MB (reused as g2)
  u16*   g1     = (u16*)p;    p += (size_t)M * 128 * 2;   // 25.6 MB
  u16*   W1b    = (u16*)p;    p += 128 * 128 * 2;
  u16*   W2b    = (u16*)p;    p += 128 * 128 * 2;
  u16*   WpT    = (u16*)p;    p += 1024 * 128 * 2;        // padded to 1024 cols
  u16*   g2     = embb;  // emb bf16 no longer needed after GEMM1

  hipMemsetAsync(deg, 0, 400128 + 400128, stream);  // deg + counts

  conv_bf16x4<<<12500, 256, 0, stream>>>(emb, embb, M * 128 / 4);
  conv_wT<<<64,  256, 0, stream>>>(W1, W1b, 128, 128 * 128);
  conv_wT<<<64,  256, 0, stream>>>(W2, W2b, 128, 128 * 128);
  conv_wT<<<512, 256, 0, stream>>>(Wp, WpT, N_USERS, 1024 * 128);

  deg_kernel<<<(E + 255) / 256, 256, 0, stream>>>(ecol, ew, deg, E);
  dis_kernel<<<(M + 255) / 256, 256, 0, stream>>>(deg, dis, M);
  bucket_kernel<<<(E + 255) / 256, 256, 0, stream>>>(erow, ecol, ew, dis, counts, srcs, norms, E);

  const int mt = (M + 127) / 128;  // 782
  // layer 1: g1 = emb @ W1 ; g2 = Agg(g1) + b1
  gemm_mfma<false><<<dim3(mt, 1), 256, 0, stream>>>(embb, W1b, nullptr, g1, nullptr, M, 128, 128);
  agg_kernel<<<(M + 3) / 4, 256, 0, stream>>>(g1, counts, srcs, norms, b1, g2, M);
  // layer 2: g1 = g2 @ W2 ; g2 = Agg(g1) + b2
  gemm_mfma<false><<<dim3(mt, 1), 256, 0, stream>>>(g2, W2b, nullptr, g1, nullptr, M, 128, 128);
  agg_kernel<<<(M + 3) / 4, 256, 0, stream>>>(g1, counts, srcs, norms, b2, g2, M);
  // predictions = g2 @ Wp + bp
  gemm_mfma<true><<<dim3(mt, 8), 256, 0, stream>>>(g2, WpT, out, nullptr, bp, M, N_USERS, N_USERS);
}

// Round 2
// 801.109 us; speedup vs baseline: 1.1096x; 1.1096x over previous
//
#include <hip/hip_runtime.h>

#define N_NODES 100000
#define N_EDGES 640000
#define HIDDEN  128
#define N_USERS 1000
#define CAP     64   // max in-degree bucket capacity (Poisson(6.4): P(>64) ~ 0)

using u16 = unsigned short;
using u32 = unsigned int;

using short8  = __attribute__((ext_vector_type(8))) short;  // 8 bf16 (4 VGPR) MFMA frag
using floatx4 = __attribute__((ext_vector_type(4))) float;  // 4 f32 acc frag

__device__ __forceinline__ u16 f2bf(float f) {
  u32 u = __float_as_uint(f);
  u32 r = u + 0x7FFFu + ((u >> 16) & 1u);   // RNE
  return (u16)(r >> 16);
}
__device__ __forceinline__ u32 pack2bf(float a, float b) {
  return (u32)f2bf(a) | ((u32)f2bf(b) << 16);
}
__device__ __forceinline__ float bflo2f(u32 v) { return __uint_as_float(v << 16); }

// ---------------- weight transpose+cast: W [128][N] f32 -> BT [Npad][128] bf16 ----------------
__global__ void conv_wT(const float* __restrict__ W, u16* __restrict__ BT, int N, int total) {
  int idx = blockIdx.x * 256 + threadIdx.x;
  if (idx >= total) return;
  int n = idx >> 7, k = idx & 127;
  float v = (n < N) ? W[(size_t)k * N + n] : 0.f;
  BT[idx] = f2bf(v);
}

// ---------------- graph prep ----------------
__global__ void deg_kernel(const int* __restrict__ col, const float* __restrict__ w,
                           float* __restrict__ deg, int E) {
  int i = blockIdx.x * 256 + threadIdx.x;
  if (i < E) atomicAdd(&deg[col[i]], w[i]);
}

__global__ void dis_kernel(const float* __restrict__ deg, float* __restrict__ dis, int M) {
  int i = blockIdx.x * 256 + threadIdx.x;
  if (i < M) {
    float d = deg[i];
    dis[i] = d > 0.f ? rsqrtf(d) : 0.f;
  }
}

__global__ void bucket_kernel(const int* __restrict__ row, const int* __restrict__ col,
                              const float* __restrict__ w, const float* __restrict__ dis,
                              int* __restrict__ counts, int2* __restrict__ pairs, int E) {
  int i = blockIdx.x * 256 + threadIdx.x;
  if (i >= E) return;
  int r = row[i], c = col[i];
  int pos = atomicAdd(&counts[c], 1);
  if (pos < CAP) {
    pairs[((size_t)c << 6) + (size_t)pos] = make_int2(r, __float_as_int(dis[r] * w[i] * dis[c]));
  }
}

// ---------------- aggregation: out[n] = bf16( b + sum_e norm*h[src] ) ----------------
// one wave per node; lane e preloads edge e's (src,norm); per edge, shfl-broadcast
// then all 64 lanes gather one 256B row of h (lane = 2 hidden dims).
__global__ __launch_bounds__(256)
void agg_kernel(const u16* __restrict__ hb, const int* __restrict__ counts,
                const int2* __restrict__ pairs,
                const float* __restrict__ bias, u16* __restrict__ out, int M) {
  int wid  = threadIdx.x >> 6;
  int lane = threadIdx.x & 63;
  int n = blockIdx.x * 4 + wid;
  if (n >= M) return;
  int cnt = counts[n];
  cnt = cnt < CAP ? cnt : CAP;
  int2 my = pairs[((size_t)n << 6) + lane];   // lanes >= cnt hold garbage, never consumed
  int   sv = my.x;
  float wv = __int_as_float(my.y);
  const u32* h32 = (const u32*)hb;
  float ax = 0.f, ay = 0.f;
  int e = 0;
  for (; e + 4 <= cnt; e += 4) {
    int   s0 = __shfl(sv, e),     s1 = __shfl(sv, e + 1);
    int   s2 = __shfl(sv, e + 2), s3 = __shfl(sv, e + 3);
    float w0 = __shfl(wv, e),     w1 = __shfl(wv, e + 1);
    float w2 = __shfl(wv, e + 2), w3 = __shfl(wv, e + 3);
    u32 h0 = h32[((size_t)s0 << 6) + lane];
    u32 h1 = h32[((size_t)s1 << 6) + lane];
    u32 h2 = h32[((size_t)s2 << 6) + lane];
    u32 h3 = h32[((size_t)s3 << 6) + lane];
    ax += w0 * bflo2f(h0 & 0xFFFFu); ay += w0 * __uint_as_float(h0 & 0xFFFF0000u);
    ax += w1 * bflo2f(h1 & 0xFFFFu); ay += w1 * __uint_as_float(h1 & 0xFFFF0000u);
    ax += w2 * bflo2f(h2 & 0xFFFFu); ay += w2 * __uint_as_float(h2 & 0xFFFF0000u);
    ax += w3 * bflo2f(h3 & 0xFFFFu); ay += w3 * __uint_as_float(h3 & 0xFFFF0000u);
  }
  for (; e < cnt; ++e) {
    int   s = __shfl(sv, e);
    float w = __shfl(wv, e);
    u32 hv = h32[((size_t)s << 6) + lane];
    ax += w * bflo2f(hv & 0xFFFFu);
    ay += w * __uint_as_float(hv & 0xFFFF0000u);
  }
  float2 b = ((const float2*)bias)[lane];
  u32 lo = (u32)f2bf(ax + b.x);
  u32 hi = (u32)f2bf(ay + b.y);
  ((u32*)out)[((size_t)n << 6) + lane] = lo | (hi << 16);
}

// ---------------- MFMA GEMM: C[M x N] = A[M x 128] @ B[128 x N] ----------------
// A row-major (bf16, or f32 converted during staging when AF32); B pre-transposed BT[Npad][128] bf16.
// block: 256 thr = 4 waves (2x2), block tile 128x128, wave tile 64x64 (4x4 of 16x16x32).
// LDS: As/Bs 128x128 bf16 each, XOR-swizzled 16B chunks (no padding) = 64 KB total.
template<bool F32OUT, bool AF32>
__global__ __launch_bounds__(256, 2)
void gemm_mfma(const void* __restrict__ Av, const u16* __restrict__ BT,
               float* __restrict__ outf, u16* __restrict__ outb,
               const float* __restrict__ bias,
               int M, int Nstore, int ldout) {
  __shared__ u16 As[128 * 128];
  __shared__ u16 Bs[128 * 128];
  const int m0 = blockIdx.x * 128;
  const int n0 = blockIdx.y * 128;
  const int tid = threadIdx.x;

  // cooperative staging: 2048 chunks of 16B; chunk c of row r goes to column-chunk c^(r&15)
  for (int i = 0; i < 8; ++i) {
    int chunk = tid + i * 256;
    int row = chunk >> 4;
    int c   = chunk & 15;
    int sw  = ((c ^ (row & 15)) << 3);
    int gr  = m0 + row;
    uint4 av = {0u, 0u, 0u, 0u};
    if (gr < M) {
      if (AF32) {
        const float4* s4 = (const float4*)((const float*)Av + ((size_t)gr << 7) + (c << 3));
        float4 lo = s4[0], hi = s4[1];
        av.x = pack2bf(lo.x, lo.y); av.y = pack2bf(lo.z, lo.w);
        av.z = pack2bf(hi.x, hi.y); av.w = pack2bf(hi.z, hi.w);
      } else {
        av = *(const uint4*)((const u16*)Av + ((size_t)gr << 7) + (c << 3));
      }
    }
    *(uint4*)(&As[(row << 7) + sw]) = av;
    uint4 bv = *(const uint4*)(BT + ((size_t)(n0 + row) << 7) + (c << 3));
    *(uint4*)(&Bs[(row << 7) + sw]) = bv;
  }
  __syncthreads();

  const int wid  = tid >> 6, lane = tid & 63;
  const int wr = (wid >> 1) << 6;       // wave row origin within block tile
  const int wc = (wid & 1) << 6;        // wave col origin
  const int lm = lane & 15, quad = lane >> 4;

  floatx4 acc[4][4] = {};
  for (int ks = 0; ks < 4; ++ks) {
    int cks = ks * 4 + quad;            // 16B-chunk index along K for this lane
    int sw  = ((cks ^ lm) << 3);
    short8 a[4], b[4];
    for (int i = 0; i < 4; ++i)
      a[i] = *(const short8*)(&As[((wr + i * 16 + lm) << 7) + sw]);
    for (int j = 0; j < 4; ++j)
      b[j] = *(const short8*)(&Bs[((wc + j * 16 + lm) << 7) + sw]);
    for (int i = 0; i < 4; ++i)
      for (int j = 0; j < 4; ++j)
        acc[i][j] = __builtin_amdgcn_mfma_f32_16x16x32_bf16(a[i], b[j], acc[i][j], 0, 0, 0);
  }

  // epilogue: D[row = quad*4 + r][col = lm] per 16x16 tile (m89-verified layout)
  for (int i = 0; i < 4; ++i) {
    int rb = m0 + wr + i * 16 + quad * 4;
    for (int j = 0; j < 4; ++j) {
      int col = n0 + wc + j * 16 + lm;
      if (col < Nstore) {
        float bv = F32OUT ? bias[col] : 0.f;
        for (int r = 0; r < 4; ++r) {
          int row = rb + r;
          if (row < M) {
            float v = acc[i][j][r];
            if (F32OUT) outf[(size_t)row * ldout + col] = v + bv;
            else        outb[((size_t)row << 7) + col]  = f2bf(v);
          }
        }
      }
    }
  }
}

// ---------------- launch ----------------
extern "C" void kernel_launch(void* const* d_in, const int* in_sizes, int n_in,
                              void* d_out, int out_size, void* d_ws, size_t ws_size,
                              hipStream_t stream) {
  const int*   eidx = (const int*)d_in[0];
  const int*   erow = eidx;
  const int*   ecol = eidx + N_EDGES;
  const float* ew   = (const float*)d_in[1];
  const float* emb  = (const float*)d_in[2];
  const float* W1   = (const float*)d_in[3];
  const float* b1   = (const float*)d_in[4];
  const float* W2   = (const float*)d_in[5];
  const float* b2   = (const float*)d_in[6];
  const float* Wp   = (const float*)d_in[7];
  const float* bp   = (const float*)d_in[8];
  float* out = (float*)d_out;

  const int M = N_NODES, E = N_EDGES;

  // workspace carve (all 128B-aligned sections)
  char* p = (char*)d_ws;
  float* deg    = (float*)p;  p += 400128;           // 100000 f32
  int*   counts = (int*)p;    p += 400128;           // 100000 i32 (adjacent to deg for one memset)
  float* dis    = (float*)p;  p += 400128;
  int2*  pairs  = (int2*)p;   p += (size_t)M * CAP * 8;   // 51.2 MB interleaved (src, norm)
  u16*   g1     = (u16*)p;    p += (size_t)M * 128 * 2;   // 25.6 MB
  u16*   g2     = (u16*)p;    p += (size_t)M * 128 * 2;   // 25.6 MB
  u16*   W1b    = (u16*)p;    p += 128 * 128 * 2;
  u16*   W2b    = (u16*)p;    p += 128 * 128 * 2;
  u16*   WpT    = (u16*)p;    p += 1024 * 128 * 2;        // padded to 1024 cols

  hipMemsetAsync(deg, 0, 400128 + 400128, stream);  // deg + counts

  conv_wT<<<64,  256, 0, stream>>>(W1, W1b, 128, 128 * 128);
  conv_wT<<<64,  256, 0, stream>>>(W2, W2b, 128, 128 * 128);
  conv_wT<<<512, 256, 0, stream>>>(Wp, WpT, N_USERS, 1024 * 128);

  deg_kernel<<<(E + 255) / 256, 256, 0, stream>>>(ecol, ew, deg, E);
  dis_kernel<<<(M + 255) / 256, 256, 0, stream>>>(deg, dis, M);
  bucket_kernel<<<(E + 255) / 256, 256, 0, stream>>>(erow, ecol, ew, dis, counts, pairs, E);

  const int mt = (M + 127) / 128;  // 782
  // layer 1: g1 = bf16(emb) @ W1 ; g2 = Agg(g1) + b1
  gemm_mfma<false, true><<<dim3(mt, 1), 256, 0, stream>>>(emb, W1b, nullptr, g1, nullptr, M, 128, 128);
  agg_kernel<<<(M + 3) / 4, 256, 0, stream>>>(g1, counts, pairs, b1, g2, M);
  // layer 2: g1 = g2 @ W2 ; g2 = Agg(g1) + b2
  gemm_mfma<false, false><<<dim3(mt, 1), 256, 0, stream>>>(g2, W2b, nullptr, g1, nullptr, M, 128, 128);
  agg_kernel<<<(M + 3) / 4, 256, 0, stream>>>(g1, counts, pairs, b2, g2, M);
  // predictions = g2 @ Wp + bp
  gemm_mfma<true, false><<<dim3(mt, 8), 256, 0, stream>>>(g2, WpT, out, nullptr, bp, M, N_USERS, N_USERS);
}